// Round 2
// baseline (547.195 us; speedup 1.0000x reference)
//
#include <hip/hip_runtime.h>
#include <math.h>

#define IN_DIM 512
#define HID 512

#define K1_BLOCKS 256
#define K1_THREADS 1024
#define K1_STRIDE (K1_BLOCKS * K1_THREADS)   // 262144 float4; %128==0 -> col4 fixed per thread
#define P1 K1_BLOCKS                          // 256 partial rows

__device__ inline float4 f4add(float4 a, float4 b) {
    return make_float4(a.x + b.x, a.y + b.y, a.z + b.z, a.w + b.w);
}

// K1: partial column sums. 256 blocks x 1024 threads, grid-stride float4 loads
// (coalesced, 1 KB per wave per iter). Thread t's float4-column group is t%128
// (block and grid strides are multiples of 128). LDS tree 1024->128, then the
// low 128 threads store one 512-float partial row per block (float4 stores).
__global__ __launch_bounds__(K1_THREADS) void k1_partial(const float* __restrict__ x,
                                                         float* __restrict__ part,
                                                         int total4) {
    const int t = threadIdx.x;
    const int gtid = blockIdx.x * K1_THREADS + t;
    const float4* __restrict__ x4 = (const float4*)x;
    float4 acc = make_float4(0.f, 0.f, 0.f, 0.f);
    for (int i = gtid; i < total4; i += K1_STRIDE) acc = f4add(acc, x4[i]);

    __shared__ float4 lds[K1_THREADS];
    lds[t] = acc;
    __syncthreads();
    if (t < 512) lds[t] = f4add(lds[t], lds[t + 512]);
    __syncthreads();
    if (t < 256) lds[t] = f4add(lds[t], lds[t + 256]);
    __syncthreads();
    if (t < 128) {
        float4 s = f4add(lds[t], lds[t + 128]);
        ((float4*)(part + (size_t)blockIdx.x * IN_DIM))[t] = s;  // col4 group == t
    }
}

// K2 (fused): finish the mean (reduce 256 partial rows, L2-resident) into LDS,
// then one 64-lane wave per output column does the three gate dot-products and
// the GRU epilogue. h = 0 => gh = bias_hh, h_new = (1-z)*n.
__global__ __launch_bounds__(256) void k2_gemv_gates(const float* __restrict__ part,
                                                     const float* __restrict__ wih,
                                                     const float* __restrict__ bih,
                                                     const float* __restrict__ bhh,
                                                     float* __restrict__ out,
                                                     float inv_n) {
    __shared__ float agg[IN_DIM];
    for (int c = threadIdx.x; c < IN_DIM; c += 256) {
        float s0 = 0.f, s1 = 0.f, s2 = 0.f, s3 = 0.f;
        const float* __restrict__ base = part + c;
#pragma unroll 4
        for (int r = 0; r < P1; r += 4) {
            s0 += base[(size_t)(r + 0) * IN_DIM];
            s1 += base[(size_t)(r + 1) * IN_DIM];
            s2 += base[(size_t)(r + 2) * IN_DIM];
            s3 += base[(size_t)(r + 3) * IN_DIM];
        }
        agg[c] = ((s0 + s1) + (s2 + s3)) * inv_n;
    }
    __syncthreads();

    const int w = threadIdx.x >> 6;      // wave in block: 0..3
    const int l = threadIdx.x & 63;      // lane
    const int j = blockIdx.x * 4 + w;    // output column 0..511

    const float4* __restrict__ a4 = (const float4*)agg;
    float4 g1 = a4[l];
    float4 g2 = a4[l + 64];

    float d[3];
#pragma unroll
    for (int gidx = 0; gidx < 3; ++gidx) {
        const float4* __restrict__ w4 =
            (const float4*)(wih + (size_t)(gidx * HID + j) * IN_DIM);
        float4 w1 = w4[l];
        float4 w2 = w4[l + 64];
        d[gidx] = w1.x * g1.x + w1.y * g1.y + w1.z * g1.z + w1.w * g1.w
                + w2.x * g2.x + w2.y * g2.y + w2.z * g2.z + w2.w * g2.w;
    }

#pragma unroll
    for (int off = 32; off > 0; off >>= 1) {
        d[0] += __shfl_down(d[0], off, 64);
        d[1] += __shfl_down(d[1], off, 64);
        d[2] += __shfl_down(d[2], off, 64);
    }

    if (l == 0) {
        float gi_r = d[0] + bih[j];
        float gi_z = d[1] + bih[HID + j];
        float gi_n = d[2] + bih[2 * HID + j];
        float r = 1.f / (1.f + expf(-(gi_r + bhh[j])));
        float z = 1.f / (1.f + expf(-(gi_z + bhh[HID + j])));
        float n = tanhf(gi_n + r * bhh[2 * HID + j]);
        out[j] = (1.f - z) * n;   // + z*h, h = 0
    }
}

extern "C" void kernel_launch(void* const* d_in, const int* in_sizes, int n_in,
                              void* d_out, int out_size, void* d_ws, size_t ws_size,
                              hipStream_t stream) {
    const float* x   = (const float*)d_in[0];  // parent_states (N, 512)
    const float* wih = (const float*)d_in[1];  // weight_ih (1536, 512)
    // d_in[2] = weight_hh: unused (h = 0 => gh = bias_hh)
    const float* bih = (const float*)d_in[3];  // bias_ih (1536,)
    const float* bhh = (const float*)d_in[4];  // bias_hh (1536,)
    float* out = (float*)d_out;

    const int n_par  = in_sizes[0] / IN_DIM;
    const int total4 = in_sizes[0] / 4;

    float* part = (float*)d_ws;  // P1 * 512 floats = 512 KB

    k1_partial<<<K1_BLOCKS, K1_THREADS, 0, stream>>>(x, part, total4);
    k2_gemv_gates<<<HID / 4, 256, 0, stream>>>(part, wih, bih, bhh, out,
                                               1.0f / (float)n_par);
}